// Round 2
// baseline (321.717 us; speedup 1.0000x reference)
//
#include <hip/hip_runtime.h>
#include <hip/hip_bf16.h>

#define Bb 512
#define Ll 64
#define Dd 1024
#define Uu 512

typedef __attribute__((ext_vector_type(8))) short short8;
typedef __attribute__((ext_vector_type(4))) float f32x4;
typedef __attribute__((ext_vector_type(4))) unsigned short u16x4;

__device__ __forceinline__ unsigned short f2bf(float x) {
  unsigned int u = __float_as_uint(x);
  u += 0x7FFF + ((u >> 16) & 1);   // RNE
  return (unsigned short)(u >> 16);
}

// ---------------- Kernel A1: h = hidden @ W2_w + W2_b  [512,512] ----------------
__global__ void k_hidden(const float* __restrict__ hidden,
                         const float* __restrict__ W2w,
                         const float* __restrict__ W2b,
                         float* __restrict__ h) {
  __shared__ float hid[8][Uu];
  const int b0 = blockIdx.x * 8;
  const int u = threadIdx.x;  // 512 threads
  for (int i = 0; i < 8; ++i) hid[i][u] = hidden[(size_t)(b0 + i) * Uu + u];
  __syncthreads();
  float acc[8] = {0.f, 0.f, 0.f, 0.f, 0.f, 0.f, 0.f, 0.f};
  for (int k = 0; k < Uu; ++k) {
    const float w = W2w[(size_t)k * Uu + u];
#pragma unroll 8
    for (int i = 0; i < 8; ++i) acc[i] += hid[i][k] * w;
  }
  const float bb = W2b[u];
  for (int i = 0; i < 8; ++i) h[(size_t)(b0 + i) * Uu + u] = acc[i] + bb;
}

// ------------- Kernel A2: W1T bf16 [U][D] from W1_w f32 [D][U] -------------
__global__ void k_w1t(const float* __restrict__ W1w, unsigned short* __restrict__ W1T) {
  __shared__ float tile[32][33];
  const int kb = blockIdx.x;  // 0..31  (D/32)
  const int ub = blockIdx.y;  // 0..15  (U/32)
  const int t = threadIdx.x;  // 256 threads
#pragma unroll
  for (int i = 0; i < 4; ++i) {
    const int idx = t + i * 256;
    const int r = idx >> 5, c = idx & 31;
    tile[r][c] = W1w[(size_t)(kb * 32 + r) * Uu + ub * 32 + c];
  }
  __syncthreads();
#pragma unroll
  for (int i = 0; i < 4; ++i) {
    const int idx = t + i * 256;
    const int ur = idx >> 5, kc = idx & 31;
    W1T[(size_t)(ub * 32 + ur) * Dd + kb * 32 + kc] = f2bf(tile[kc][ur]);
  }
}

// ---------------- Kernel B: fused score GEMM + tanh + V dot + softmax + context ----------------
// One block per batch b. Block tile: 64 rows (all L) x 512 cols (all U).
// 8 waves, wave w owns cols [w*64, w*64+64). Wave tile 64x64 -> acc[4][4] of 16x16x32 MFMA.
// LDS rows are 128 B (64 bf16); 16B-slot XOR swizzle: slot ^= (row & 7) -> conflict-free.
__global__ void __launch_bounds__(512) k_fused(
    const float* __restrict__ features,
    const unsigned short* __restrict__ W1T,
    const float* __restrict__ W1b,
    const float* __restrict__ h,
    const float* __restrict__ Vw,
    const float* __restrict__ Vb,
    float* __restrict__ out_ctx,
    float* __restrict__ out_attn) {
  __shared__ __align__(16) unsigned char smem[73728];  // As: 64*128 B, Bs: 512*128 B
  unsigned char* smA = smem;
  unsigned char* smB = smem + 8192;
  float (*lp)[8] = (float(*)[8])smem;           // reuse As region after GEMM
  float* attn_s = (float*)(smem + 2048);

  const int b = blockIdx.x;
  const int tid = threadIdx.x;
  const int lane = tid & 63;
  const int w = tid >> 6;   // wave id = col block (0..7)
  const int l15 = lane & 15;
  const int lg = lane >> 4;  // 0..3

  const float* featB = features + (size_t)b * Ll * Dd;

  f32x4 acc[4][4];
#pragma unroll
  for (int mi = 0; mi < 4; ++mi)
#pragma unroll
    for (int ni = 0; ni < 4; ++ni) acc[mi][ni] = (f32x4){0.f, 0.f, 0.f, 0.f};

  for (int kt = 0; kt < Dd / 64; ++kt) {
    const int k0 = kt * 64;
    // ---- stage A: features[b] 64 rows x 64 k, f32 -> bf16, swizzled ----
#pragma unroll
    for (int i = 0; i < 2; ++i) {
      const int c = tid + i * 512;     // 0..1023
      const int row = c >> 4;          // 0..63
      const int pos = c & 15;          // float4 index within 64-k row
      const float4 v = *reinterpret_cast<const float4*>(featB + (size_t)row * Dd + k0 + pos * 4);
      u16x4 p = {f2bf(v.x), f2bf(v.y), f2bf(v.z), f2bf(v.w)};
      const int slot = pos >> 1;
      *reinterpret_cast<u16x4*>(smA + row * 128 + ((slot ^ (row & 7)) << 4) + (pos & 1) * 8) = p;
    }
    // ---- stage B: W1T 512 u x 64 k bf16, swizzled ----
#pragma unroll
    for (int i = 0; i < 8; ++i) {
      const int c = i * 512 + tid;     // 0..4095
      const int uu = c >> 3;           // 0..511
      const int ch = c & 7;            // 16B chunk (8 k)
      const int4 v = *reinterpret_cast<const int4*>(W1T + (size_t)uu * Dd + k0 + ch * 8);
      *reinterpret_cast<int4*>(smB + uu * 128 + ((ch ^ (uu & 7)) << 4)) = v;
    }
    __syncthreads();
#pragma unroll
    for (int kk = 0; kk < 2; ++kk) {
      const int slot = kk * 4 + lg;
      short8 afr[4], bfr[4];
#pragma unroll
      for (int mi = 0; mi < 4; ++mi) {
        const int row = mi * 16 + l15;
        afr[mi] = *reinterpret_cast<const short8*>(smA + row * 128 + ((slot ^ (row & 7)) << 4));
      }
#pragma unroll
      for (int ni = 0; ni < 4; ++ni) {
        const int uu = w * 64 + ni * 16 + l15;
        bfr[ni] = *reinterpret_cast<const short8*>(smB + uu * 128 + ((slot ^ (uu & 7)) << 4));
      }
#pragma unroll
      for (int mi = 0; mi < 4; ++mi)
#pragma unroll
        for (int ni = 0; ni < 4; ++ni)
          acc[mi][ni] = __builtin_amdgcn_mfma_f32_16x16x32_bf16(afr[mi], bfr[ni], acc[mi][ni], 0, 0, 0);
    }
    __syncthreads();
  }

  // ---- epilogue: tanh + dot with V_w, per-row partials ----
  float part[4][4];
#pragma unroll
  for (int mi = 0; mi < 4; ++mi)
#pragma unroll
    for (int r = 0; r < 4; ++r) part[mi][r] = 0.f;

#pragma unroll
  for (int ni = 0; ni < 4; ++ni) {
    const int col = w * 64 + ni * 16 + l15;
    const float hb = h[(size_t)b * Uu + col];
    const float b1 = W1b[col];
    const float vw = Vw[col];
#pragma unroll
    for (int mi = 0; mi < 4; ++mi) {
#pragma unroll
      for (int r = 0; r < 4; ++r) {
        const float x = acc[mi][ni][r] + b1 + hb;
        const float e = __expf(2.f * x);           // tanh via hw exp
        part[mi][r] += vw * (e - 1.f) / (e + 1.f);
      }
    }
  }
  // reduce across the 16 lanes that share a row (l15)
#pragma unroll
  for (int mi = 0; mi < 4; ++mi)
#pragma unroll
    for (int r = 0; r < 4; ++r) {
      float v = part[mi][r];
      v += __shfl_xor(v, 1);
      v += __shfl_xor(v, 2);
      v += __shfl_xor(v, 4);
      v += __shfl_xor(v, 8);
      if (l15 == 0) lp[mi * 16 + lg * 4 + r][w] = v;  // row-local partial per wave
    }
  __syncthreads();

  // ---- softmax over the 64 rows (one wave) ----
  if (tid < 64) {
    float lgv = Vb[0];
#pragma unroll
    for (int j = 0; j < 8; ++j) lgv += lp[tid][j];
    float m = lgv;
#pragma unroll
    for (int off = 32; off > 0; off >>= 1) m = fmaxf(m, __shfl_xor(m, off));
    const float e = __expf(lgv - m);
    float s = e;
#pragma unroll
    for (int off = 32; off > 0; off >>= 1) s += __shfl_xor(s, off);
    const float a = e / s;
    attn_s[tid] = a;
    out_attn[(size_t)b * 64 + tid] = a;
  }
  __syncthreads();

  // ---- context: out_ctx[b][d] = sum_l attn[l] * features[b][l][d] ----
  const int d0 = tid * 2;
  float2 c2 = {0.f, 0.f};
#pragma unroll 8
  for (int l = 0; l < 64; ++l) {
    const float a = attn_s[l];
    const float2 f = *reinterpret_cast<const float2*>(featB + (size_t)l * Dd + d0);
    c2.x += a * f.x;
    c2.y += a * f.y;
  }
  *reinterpret_cast<float2*>(out_ctx + (size_t)b * Dd + d0) = c2;
}

extern "C" void kernel_launch(void* const* d_in, const int* in_sizes, int n_in,
                              void* d_out, int out_size, void* d_ws, size_t ws_size,
                              hipStream_t stream) {
  const float* features = (const float*)d_in[0];
  const float* hidden   = (const float*)d_in[1];
  const float* W1w      = (const float*)d_in[2];
  const float* W1b      = (const float*)d_in[3];
  const float* W2w      = (const float*)d_in[4];
  const float* W2b      = (const float*)d_in[5];
  const float* Vw       = (const float*)d_in[6];
  const float* Vb       = (const float*)d_in[7];
  float* out_ctx  = (float*)d_out;                         // [512][1024]
  float* out_attn = (float*)d_out + (size_t)Bb * Dd;       // [512][64]

  float* h = (float*)d_ws;                                              // 1 MB
  unsigned short* W1T = (unsigned short*)((char*)d_ws + (size_t)Bb * Uu * 4);  // 1 MB bf16

  k_hidden<<<64, 512, 0, stream>>>(hidden, W2w, W2b, h);
  k_w1t<<<dim3(32, 16), 256, 0, stream>>>(W1w, W1T);
  k_fused<<<Bb, 512, 0, stream>>>(features, W1T, W1b, h, Vw, Vb, out_ctx, out_attn);
}

// Round 4
// 285.545 us; speedup vs baseline: 1.1267x; 1.1267x over previous
//
#include <hip/hip_runtime.h>
#include <hip/hip_bf16.h>

#define Bb 512
#define Ll 64
#define Dd 1024
#define Uu 512

typedef __attribute__((ext_vector_type(8))) short short8;
typedef __attribute__((ext_vector_type(4))) float f32x4;
typedef __attribute__((ext_vector_type(4))) unsigned short u16x4;

__device__ __forceinline__ unsigned short f2bf(float x) {
  unsigned int u = __float_as_uint(x);
  u += 0x7FFF + ((u >> 16) & 1);   // RNE
  return (unsigned short)(u >> 16);
}

// CK-style cast pattern for global_load_lds (LDS aperture: low 32 bits are the offset)
__device__ __forceinline__ void gld16(const void* g, void* l) {
  auto gp = reinterpret_cast<const __attribute__((address_space(1))) unsigned int*>(
      reinterpret_cast<uintptr_t>(g));
  auto lp = reinterpret_cast<__attribute__((address_space(3))) unsigned int*>(
      reinterpret_cast<uintptr_t>(l));
  __builtin_amdgcn_global_load_lds(gp, lp, 16, 0, 0);
}

// ---------------- k_prep: role-split {h = hidden@W2+b} and {W1s swizzled bf16 image} --------
// blocks 0..127: hidden-role, 4 batches each.
// blocks 128..383: W1s-role, 256 blocks covering (kb 0..31) x (ub 0..7) tiles of 32k x 64u.
// W1s image layout (per kt of 32 k): byte = u*64 + ((ch ^ (u&3))<<4) + j*2,
//   ch = (k&31)>>3 (8-k chunk), j = k&7. Linear 16B-per-lane DMA in k_fused reproduces it in LDS.
__global__ void __launch_bounds__(512) k_prep(const float* __restrict__ hidden,
                                              const float* __restrict__ W2w,
                                              const float* __restrict__ W2b,
                                              const float* __restrict__ W1w,
                                              float* __restrict__ h,
                                              unsigned char* __restrict__ W1s) {
  const int t = threadIdx.x;
  if (blockIdx.x < 128) {
    __shared__ float hid[4][Uu];
    const int b0 = blockIdx.x * 4;
#pragma unroll
    for (int i = 0; i < 4; ++i) hid[i][t] = hidden[(size_t)(b0 + i) * Uu + t];
    __syncthreads();
    float a0 = 0.f, a1 = 0.f, a2 = 0.f, a3 = 0.f;
    for (int k0 = 0; k0 < Uu; k0 += 8) {
      float wv[8];
#pragma unroll
      for (int j = 0; j < 8; ++j) wv[j] = W2w[(size_t)(k0 + j) * Uu + t];  // 8 loads in flight
#pragma unroll
      for (int j = 0; j < 8; ++j) {
        a0 += hid[0][k0 + j] * wv[j];
        a1 += hid[1][k0 + j] * wv[j];
        a2 += hid[2][k0 + j] * wv[j];
        a3 += hid[3][k0 + j] * wv[j];
      }
    }
    const float bb = W2b[t];
    h[(size_t)(b0 + 0) * Uu + t] = a0 + bb;
    h[(size_t)(b0 + 1) * Uu + t] = a1 + bb;
    h[(size_t)(b0 + 2) * Uu + t] = a2 + bb;
    h[(size_t)(b0 + 3) * Uu + t] = a3 + bb;
  } else {
    const int id = blockIdx.x - 128;  // 0..255
    const int kb = id >> 3;           // 0..31
    const int ub = id & 7;            // 0..7
    __shared__ float tile[32][68];    // [k][u], padded
    {
      const int r = t >> 4;           // 0..31
      const int c4 = t & 15;          // 0..15
      const float4 v = *reinterpret_cast<const float4*>(
          &W1w[(size_t)(kb * 32 + r) * Uu + ub * 64 + c4 * 4]);
      *reinterpret_cast<float4*>(&tile[r][c4 * 4]) = v;  // row stride 272B = 17*16, aligned
    }
    __syncthreads();
    if (t < 256) {
      const int ul = t >> 2;          // 0..63
      const int ch = t & 3;           // 0..3
      const int u = ub * 64 + ul;
      unsigned int px[4];
#pragma unroll
      for (int q = 0; q < 4; ++q) {
        const unsigned int lo = f2bf(tile[ch * 8 + q * 2][ul]);
        const unsigned int hi = f2bf(tile[ch * 8 + q * 2 + 1][ul]);
        px[q] = lo | (hi << 16);
      }
      const int sw = ch ^ (u & 3);
      uint4 pack;
      pack.x = px[0]; pack.y = px[1]; pack.z = px[2]; pack.w = px[3];
      *reinterpret_cast<uint4*>(&W1s[(size_t)kb * 32768 + u * 64 + sw * 16]) = pack;
    }
  }
}

// ---------------- k_fused v2: 2 batches/block, 2-phase dbuf pipeline ----------------
// 1024 threads = 16 waves (2 batch-rows x 8 col-blocks). Wave tile 64x64, acc[4][4].
// LDS: bufA 2x8KB (128 rows x 64B), bufB 2x32KB (512 rows x 64B). BK=32, 32 K-steps.
// B staged by global_load_lds from pre-swizzled W1s (linear DMA); A reg-staged f32->bf16.
// Per iter: STAGE(next) -> ds_read frags(cur) -> 16 MFMA -> write A(next) -> barrier.
__global__ void __launch_bounds__(1024) k_fused(
    const float* __restrict__ features,
    const unsigned char* __restrict__ W1s,
    const float* __restrict__ W1b,
    const float* __restrict__ h,
    const float* __restrict__ Vw,
    const float* __restrict__ Vb,
    float* __restrict__ out_ctx,
    float* __restrict__ out_attn) {
  __shared__ __align__(16) unsigned char smem[81920];
  unsigned char* bufA = smem;           // 2 x 8192
  unsigned char* bufB = smem + 16384;   // 2 x 32768

  const int b0 = blockIdx.x * 2;
  const int tid = threadIdx.x;
  const int lane = tid & 63;
  const int w = tid >> 6;     // 0..15
  const int wr = w >> 3;      // 0..1 : batch row
  const int wc = w & 7;       // 0..7 : 64-col block
  const int l15 = lane & 15;
  const int lg = lane >> 4;

  const float* featB = features + (size_t)b0 * Ll * Dd;  // 128 rows x 1024

  // A staging: thread stages row ar (0..127), float4 chunk ap (0..7) of each 32-k window
  const int ar = tid >> 3;
  const int ap = tid & 7;
  const float* ag = featB + (size_t)ar * Dd + ap * 4;
  const int awoff = ar * 64 + (((ap >> 1) ^ (ar & 3)) << 4) + (ap & 1) * 8;

  // fragment read offsets (bijective XOR swizzle -> each wave read covers contiguous 1KB)
  const int swl = (lg ^ (l15 & 3)) << 4;
  const int aoff0 = (wr * 64 + l15) * 64 + swl;        // + mi*1024
  const int boff0 = (wc * 64 + l15) * 64 + swl;        // + ni*1024

  f32x4 acc[4][4];
#pragma unroll
  for (int mi = 0; mi < 4; ++mi)
#pragma unroll
    for (int ni = 0; ni < 4; ++ni) acc[mi][ni] = (f32x4){0.f, 0.f, 0.f, 0.f};

  // ---- prologue: stage kt=0 into buffer 0 ----
  {
    const float4 va = *reinterpret_cast<const float4*>(ag);
    const unsigned char* src = W1s + (size_t)(w * 2) * 1024 + lane * 16;
    unsigned char* dst = bufB + (w * 2) * 1024;  // wave-uniform base
    gld16(src, dst);
    gld16(src + 1024, dst + 1024);
    u16x4 pa = {f2bf(va.x), f2bf(va.y), f2bf(va.z), f2bf(va.w)};
    *reinterpret_cast<u16x4*>(bufA + awoff) = pa;
  }
  __syncthreads();

  for (int kt = 0; kt < 32; ++kt) {
    const int cur = kt & 1;
    const unsigned char* cA = bufA + cur * 8192;
    const unsigned char* cB = bufB + cur * 32768;
    float4 va;
    if (kt < 31) {
      va = *reinterpret_cast<const float4*>(ag + (kt + 1) * 32);        // A prefetch (reg)
      const unsigned char* src = W1s + (size_t)(kt + 1) * 32768 + (w * 2) * 1024 + lane * 16;
      unsigned char* dst = bufB + (cur ^ 1) * 32768 + (w * 2) * 1024;
      gld16(src, dst);                                                  // B prefetch (DMA)
      gld16(src + 1024, dst + 1024);
    }
    short8 afr[4], bfr[4];
#pragma unroll
    for (int mi = 0; mi < 4; ++mi)
      afr[mi] = *reinterpret_cast<const short8*>(cA + aoff0 + mi * 1024);
#pragma unroll
    for (int ni = 0; ni < 4; ++ni)
      bfr[ni] = *reinterpret_cast<const short8*>(cB + boff0 + ni * 1024);
#pragma unroll
    for (int mi = 0; mi < 4; ++mi)
#pragma unroll
      for (int ni = 0; ni < 4; ++ni)
        acc[mi][ni] = __builtin_amdgcn_mfma_f32_16x16x32_bf16(afr[mi], bfr[ni], acc[mi][ni], 0, 0, 0);
    if (kt < 31) {
      u16x4 pa = {f2bf(va.x), f2bf(va.y), f2bf(va.z), f2bf(va.w)};
      *reinterpret_cast<u16x4*>(bufA + (cur ^ 1) * 8192 + awoff) = pa;  // A write (next)
    }
    __syncthreads();  // drains vmcnt+lgkmcnt: next buffer complete, cur reads done
  }

  // ---- epilogue: tanh + V dot ----
  float part[4][4];
#pragma unroll
  for (int mi = 0; mi < 4; ++mi)
#pragma unroll
    for (int r = 0; r < 4; ++r) part[mi][r] = 0.f;

  const int bt = b0 + wr;
#pragma unroll
  for (int ni = 0; ni < 4; ++ni) {
    const int col = wc * 64 + ni * 16 + l15;
    const float hb = h[(size_t)bt * Uu + col];
    const float b1 = W1b[col];
    const float vw = Vw[col];
#pragma unroll
    for (int mi = 0; mi < 4; ++mi)
#pragma unroll
      for (int r = 0; r < 4; ++r) {
        const float x = acc[mi][ni][r] + b1 + hb;
        const float e = __expf(2.f * x);
        part[mi][r] += vw * (1.f - 2.f / (e + 1.f));   // tanh, inf-safe
      }
  }
  float* lpart = (float*)smem;               // [128 rows][8 wc] = 4KB (bufA reuse)
  float* attn_s = (float*)(smem + 4096);     // [128]
#pragma unroll
  for (int mi = 0; mi < 4; ++mi)
#pragma unroll
    for (int r = 0; r < 4; ++r) {
      float v = part[mi][r];
      v += __shfl_xor(v, 1);
      v += __shfl_xor(v, 2);
      v += __shfl_xor(v, 4);
      v += __shfl_xor(v, 8);
      if (l15 == 0) lpart[(wr * 64 + mi * 16 + lg * 4 + r) * 8 + wc] = v;
    }
  __syncthreads();

  // ---- softmax per batch (waves 0 and 1) ----
  if (tid < 128) {
    const int bi = tid >> 6;
    const int row = tid & 63;
    float lgv = Vb[0];
#pragma unroll
    for (int j = 0; j < 8; ++j) lgv += lpart[(bi * 64 + row) * 8 + j];
    float m = lgv;
#pragma unroll
    for (int off = 32; off > 0; off >>= 1) m = fmaxf(m, __shfl_xor(m, off));
    const float e = __expf(lgv - m);
    float s = e;
#pragma unroll
    for (int off = 32; off > 0; off >>= 1) s += __shfl_xor(s, off);
    const float a = e / s;
    attn_s[tid] = a;
    out_attn[(size_t)(b0 + bi) * 64 + row] = a;
  }
  __syncthreads();

  // ---- context: 512 threads per batch, 2 d-columns each ----
  {
    const int bi = tid >> 9;
    const int dq = tid & 511;
    const float* fb = features + (size_t)(b0 + bi) * Ll * Dd + dq * 2;
    float2 c2 = {0.f, 0.f};
#pragma unroll 8
    for (int l = 0; l < 64; ++l) {
      const float a = attn_s[bi * 64 + l];
      const float2 f = *reinterpret_cast<const float2*>(fb + (size_t)l * Dd);
      c2.x += a * f.x;
      c2.y += a * f.y;
    }
    *reinterpret_cast<float2*>(&out_ctx[(size_t)(b0 + bi) * Dd + dq * 2]) = c2;
  }
}

extern "C" void kernel_launch(void* const* d_in, const int* in_sizes, int n_in,
                              void* d_out, int out_size, void* d_ws, size_t ws_size,
                              hipStream_t stream) {
  const float* features = (const float*)d_in[0];
  const float* hidden   = (const float*)d_in[1];
  const float* W1w      = (const float*)d_in[2];
  const float* W1b      = (const float*)d_in[3];
  const float* W2w      = (const float*)d_in[4];
  const float* W2b      = (const float*)d_in[5];
  const float* Vw       = (const float*)d_in[6];
  const float* Vb       = (const float*)d_in[7];
  float* out_ctx  = (float*)d_out;                    // [512][1024]
  float* out_attn = (float*)d_out + (size_t)Bb * Dd;  // [512][64]

  float* h = (float*)d_ws;                                  // 1 MB
  unsigned char* W1s = (unsigned char*)d_ws + (1u << 20);   // 1 MB swizzled bf16 image

  k_prep<<<384, 512, 0, stream>>>(hidden, W2w, W2b, W1w, h, W1s);
  k_fused<<<256, 1024, 0, stream>>>(features, W1s, W1b, h, Vw, Vb, out_ctx, out_attn);
}